// Round 3
// baseline (1062.396 us; speedup 1.0000x reference)
//
#include <hip/hip_runtime.h>
#include <math.h>

typedef __bf16 bf16x8 __attribute__((ext_vector_type(8)));
typedef float f32x4 __attribute__((ext_vector_type(4)));

#define BM 256
#define BN 128
#define BK 32

__device__ __forceinline__ unsigned short f2bf(float f) {
    union { float f; unsigned u; } x; x.f = f;
    unsigned r = x.u + 0x7FFFu + ((x.u >> 16) & 1u);
    return (unsigned short)(r >> 16);
}

// erf-GELU via Abramowitz-Stegun 7.1.26 (|err| <= 1.5e-7), branchless.
__device__ __forceinline__ float fast_gelu(float h) {
    const float z  = __builtin_fabsf(h) * 0.70710678118654752f;
    const float t  = __builtin_amdgcn_rcpf(__builtin_fmaf(0.3275911f, z, 1.0f));
    float p = 1.061405429f;
    p = __builtin_fmaf(p, t, -1.453152027f);
    p = __builtin_fmaf(p, t,  1.421413741f);
    p = __builtin_fmaf(p, t, -0.284496736f);
    p = __builtin_fmaf(p, t,  0.254829592f);
    const float ez = __builtin_amdgcn_exp2f(-z * z * 1.4426950408889634f);
    float erfz = __builtin_fmaf(-p * t, ez, 1.0f);
    erfz = (h < 0.0f) ? -erfz : erfz;
    return 0.5f * h * (1.0f + erfz);
}

#define GLOAD_LDS16(GP, LP)                                                      \
    __builtin_amdgcn_global_load_lds(                                            \
        (const __attribute__((address_space(1))) unsigned int*)(GP),             \
        (__attribute__((address_space(3))) unsigned int*)(LP), 16, 0, 0)

// ---- 256x128 tile, BK=32, 48 KB LDS -> 2 blocks/CU (the occupancy lever) ----
// Per K-tile: 2 phases. P_a: {read B(2)+A-h0(4); stage Ah0',B'; bar; lgkm0;
// 8 MFMA; vmcnt(2); bar}  P_b: {read A-h1(4); stage Ah1'; bar; lgkm0; 8 MFMA;
// vmcnt(1); bar}.  Per-thread outstanding loads cycle 1->3->1; vmcnt(2)
// retires Ah1(t) (read by P_b(t)), vmcnt(1) retires Ah0',B' (read by
// P_a(t+1)); every confirm precedes a barrier (cross-wave visible); every
// stage targets a region whose last read was >=1 barrier earlier.
//
// LDS swizzle for 64-byte rows (4 16B-chunks/row): logical k-slice q of row r
// lives at phys chunk (q + ((r>>1)&3)) & 3.  Read lane (q, lr) with 16-aligned
// row base -> pc = ((q + (lr>>1)) & 3): every aligned lane-octet covers all 32
// banks exactly once (conflict-free).  gload_lds dest stays linear; the
// inverse permutation is applied on the per-lane GLOBAL source chunk:
// g = ((lane&3) - ((lane>>3)&3)) & 3.

#define STAGE_A(sl, h, kto)                                                      \
    GLOAD_LDS16(Ag + (size_t)((h) * 128) * K + (kto), &As[sl][(h) * 128 * BK + aBase])
#define STAGE_B(sl, kto)                                                         \
    GLOAD_LDS16(Bg + (kto), &Bs[sl][aBase])

#define LDA(sl, rh) do {                                                         \
    const unsigned short* _pa = &As[sl][((rh) * 128 + wm * 64 + lr) * BK + pc];  \
    _Pragma("unroll") for (int _i = 0; _i < 4; ++_i)                             \
        af[_i] = *(const bf16x8*)&_pa[_i * 16 * BK];                             \
} while (0)

#define LDB(sl) do {                                                             \
    const unsigned short* _pb = &Bs[sl][(wn * 32 + lr) * BK + pc];               \
    _Pragma("unroll") for (int _j = 0; _j < 2; ++_j)                             \
        bfr[_j] = *(const bf16x8*)&_pb[_j * 16 * BK];                            \
} while (0)

#define MM(rh) do {                                                              \
    _Pragma("unroll") for (int _i = 0; _i < 4; ++_i)                             \
    _Pragma("unroll") for (int _j = 0; _j < 2; ++_j)                             \
        acc[(rh) * 4 + _i][_j] = __builtin_amdgcn_mfma_f32_16x16x32_bf16(        \
            af[_i], bfr[_j], acc[(rh) * 4 + _i][_j], 0, 0, 0);                   \
} while (0)

// C = A * Bt^T (+bias fp32, optional erf-GELU).
// A: [localRows][K] bf16 row-major.  Bt: [E][N][K] bf16 (K contiguous).
template <bool GELU, bool OUT_F32>
__global__ __launch_bounds__(512, 4) void gemm_bt(
    const unsigned short* __restrict__ A,
    const unsigned short* __restrict__ Bt,
    const float* __restrict__ bias,
    void* __restrict__ Cv,
    int N, int K, int groupStart, int eStride, int groupPitch)
{
    __shared__ __attribute__((aligned(16))) unsigned short As[2][BM * BK]; // 32 KB
    __shared__ __attribute__((aligned(16))) unsigned short Bs[2][BN * BK]; // 16 KB

    const int tid  = threadIdx.x;
    const int lane = tid & 63;
    const int w    = tid >> 6;        // 0..7
    const int wm   = w & 1;           // 64-row stripe inside each 128-row half
    const int wn   = w >> 1;          // 32-col stripe of the 128 cols

    // Bijective XCD-chunked block swizzle (all grids have total % 8 == 0):
    // dispatch-consecutive blocks on one XCD process a contiguous tile range.
    const int gx = (int)gridDim.x;
    const unsigned total = gridDim.x * gridDim.y;
    const unsigned orig  = blockIdx.y * gridDim.x + blockIdx.x;
    const unsigned nid   = (orig & 7u) * (total >> 3) + (orig >> 3);
    const int bx = (int)(nid % (unsigned)gx);
    const int by = (int)(nid / (unsigned)gx);

    const int rowBase = by * BM;
    const int colBase = bx * BN;
    const int e = (groupStart + (by >> 3) * eStride) & 7;

    // Staging: wave w covers rows/cols [w*16, +16); ONE gload per thread per
    // 8 KB unit (16 rows x 32k).  lane -> row w*16 + (lane>>2), phys chunk
    // lane&3; global source chunk g = ((lane&3) - ((lane>>3)&3)) & 3.
    const int g = ((lane & 3) - ((lane >> 3) & 3)) & 3;
    const unsigned short* Ag = A + (size_t)(rowBase + w * 16 + (lane >> 2)) * K + g * 8;
    const unsigned short* Bg = Bt + (size_t)e * N * K
                              + (size_t)(colBase + w * 16 + (lane >> 2)) * K + g * 8;
    const int aBase = w * 16 * BK;   // LDS dest base (shorts) for this wave

    const int lr = lane & 15;
    const int q  = lane >> 4;
    const int pc = ((q + (lr >> 1)) & 3) * 8;   // phys chunk of slice q, in shorts

    f32x4 acc[8][2];
    #pragma unroll
    for (int i = 0; i < 8; ++i)
        #pragma unroll
        for (int j = 0; j < 2; ++j)
            acc[i][j] = (f32x4){0.f, 0.f, 0.f, 0.f};

    bf16x8 af[4], bfr[2];

    const int NT = K / BK;   // 32 (K=1024) or 128 (K=4096)

    // Prologue: tile 0 -> buf0.  vmcnt(1) retires Ah0,B; Ah1 stays in flight.
    STAGE_A(0, 0, 0);
    STAGE_B(0, 0);
    STAGE_A(0, 1, 0);
    asm volatile("s_waitcnt vmcnt(1)" ::: "memory");
    __builtin_amdgcn_s_barrier();
    asm volatile("" ::: "memory");

    for (int t = 0; t < NT; ++t) {
        const int sl  = t & 1;
        const int ns  = sl ^ 1;
        const int ktn = (t + 1 < NT) ? (t + 1) * BK : 0;  // wrap keeps ledger exact

        // P_a: rows half 0  | stage Ah0(t+1), B(t+1)
        LDB(sl); LDA(sl, 0);
        STAGE_A(ns, 0, ktn);
        STAGE_B(ns, ktn);
        __builtin_amdgcn_s_barrier();
        asm volatile("s_waitcnt lgkmcnt(0)");
        __builtin_amdgcn_s_setprio(1); MM(0); __builtin_amdgcn_s_setprio(0);
        asm volatile("s_waitcnt vmcnt(2)" ::: "memory");   // retires Ah1(t)
        __builtin_amdgcn_s_barrier();
        asm volatile("" ::: "memory");

        // P_b: rows half 1 (bfr reused) | stage Ah1(t+1)
        LDA(sl, 1);
        STAGE_A(ns, 1, ktn);
        __builtin_amdgcn_s_barrier();
        asm volatile("s_waitcnt lgkmcnt(0)");
        __builtin_amdgcn_s_setprio(1); MM(1); __builtin_amdgcn_s_setprio(0);
        asm volatile("s_waitcnt vmcnt(1)" ::: "memory");   // retires Ah0',B'
        __builtin_amdgcn_s_barrier();
        asm volatile("" ::: "memory");
    }
    asm volatile("s_waitcnt vmcnt(0)" ::: "memory");  // drain wrapped tail stages

    // Epilogue.  C/D layout: col = lane&15, row = (lane>>4)*4 + reg   [m89]
    const float* be = bias + (size_t)e * N;
    float bj[2];
    #pragma unroll
    for (int j = 0; j < 2; ++j)
        bj[j] = be[colBase + wn * 32 + j * 16 + lr];

    #pragma unroll
    for (int rh = 0; rh < 2; ++rh)
    #pragma unroll
    for (int i = 0; i < 4; ++i)
    #pragma unroll
    for (int r = 0; r < 4; ++r) {
        const int rowLocal = rowBase + rh * 128 + wm * 64 + i * 16 + q * 4 + r;
        const int rowG = (rowLocal >> 11) * groupPitch + (rowLocal & 2047);
        #pragma unroll
        for (int j = 0; j < 2; ++j) {
            const int col = colBase + wn * 32 + j * 16 + lr;
            float v = acc[rh * 4 + i][j][r] + bj[j];
            if (GELU) v = fast_gelu(v);
            if (OUT_F32)
                ((float*)Cv)[(size_t)rowG * N + col] = v;
            else
                ((unsigned short*)Cv)[(size_t)rowG * N + col] = f2bf(v);
        }
    }
}

// W fp32 [R][C] (expert = blockIdx.z) -> Wt bf16 [C][R]
__global__ __launch_bounds__(256) void transpose_cvt(
    const float* __restrict__ W, unsigned short* __restrict__ Wt,
    int R, int C)
{
    __shared__ unsigned short t64[64][68];
    const int t = threadIdx.x;
    const int r0 = blockIdx.y * 64, c0 = blockIdx.x * 64;
    const float* Wp = W + (size_t)blockIdx.z * R * C;
    unsigned short* Wtp = Wt + (size_t)blockIdx.z * R * C;

    #pragma unroll
    for (int p = 0; p < 4; ++p) {
        const int row = p * 16 + (t >> 4);
        const int c4  = (t & 15) * 4;
        float4 v = *(const float4*)&Wp[(size_t)(r0 + row) * C + c0 + c4];
        t64[row][c4 + 0] = f2bf(v.x);
        t64[row][c4 + 1] = f2bf(v.y);
        t64[row][c4 + 2] = f2bf(v.z);
        t64[row][c4 + 3] = f2bf(v.w);
    }
    __syncthreads();
    #pragma unroll
    for (int p = 0; p < 4; ++p) {
        const int oc = p * 16 + (t >> 4);
        const int r4 = (t & 15) * 4;
        ushort4 o;
        o.x = t64[r4 + 0][oc];
        o.y = t64[r4 + 1][oc];
        o.z = t64[r4 + 2][oc];
        o.w = t64[r4 + 3][oc];
        *(ushort4*)&Wtp[(size_t)(c0 + oc) * R + r0 + r4] = o;
    }
}

__global__ __launch_bounds__(256) void cvt_f32_bf16(
    const float* __restrict__ in, unsigned short* __restrict__ out, long long n)
{
    long long i = ((long long)blockIdx.x * 256 + threadIdx.x) * 4;
    if (i < n) {
        float4 v = *(const float4*)&in[i];
        ushort4 o;
        o.x = f2bf(v.x); o.y = f2bf(v.y); o.z = f2bf(v.z); o.w = f2bf(v.w);
        *(ushort4*)&out[i] = o;
    }
}

extern "C" void kernel_launch(void* const* d_in, const int* in_sizes, int n_in,
                              void* d_out, int out_size, void* d_ws, size_t ws_size,
                              hipStream_t stream) {
    const float* x  = (const float*)d_in[0];
    const float* w1 = (const float*)d_in[1];
    const float* b1 = (const float*)d_in[2];
    const float* w2 = (const float*)d_in[3];
    const float* b2 = (const float*)d_in[4];
    float* out = (float*)d_out;
    unsigned short* ws = (unsigned short*)d_ws;

    const int E = 8, D = 1024, F = 4096, Bdim = 2, Cap = 2048;
    const int T = E * Cap;                       // 16384
    const size_t xbE = (size_t)Bdim * T * D;     // 33,554,432
    const size_t wE  = (size_t)E * D * F;        // 33,554,432
    const size_t gE  = (size_t)Cap * F;          // 8,388,608 (H elems per group)

    dim3 blk(256);
    dim3 gblk(512);
    const size_t fullBytes = (xbE + 2 * wE + gE) * 2;   // 218,103,808

    if (ws_size >= fullBytes) {
        // FULL path: everything converted once, groups batched.
        unsigned short* xb  = ws;
        unsigned short* w1t = ws + xbE;
        unsigned short* w2t = ws + xbE + wE;
        unsigned short* H   = ws + xbE + 2 * wE;
        int gpc = (int)((ws_size / 2 - (xbE + 2 * wE)) / gE);
        if (gpc > 16) gpc = 16;
        if (gpc < 1)  gpc = 1;

        cvt_f32_bf16<<<(unsigned)((xbE / 4 + 255) / 256), blk, 0, stream>>>(x, xb, (long long)xbE);
        transpose_cvt<<<dim3(F / 64, D / 64, E), blk, 0, stream>>>(w1, w1t, D, F);
        transpose_cvt<<<dim3(D / 64, F / 64, E), blk, 0, stream>>>(w2, w2t, F, D);

        for (int g0 = 0; g0 < Bdim * E; g0 += gpc) {
            const int ng = (g0 + gpc <= Bdim * E) ? gpc : (Bdim * E - g0);
            gemm_bt<true, false><<<dim3(F / BN, ng * 8), gblk, 0, stream>>>(
                xb + (size_t)g0 * Cap * D, w1t, b1, H, F, D, g0, 1, 2048);
            gemm_bt<false, true><<<dim3(D / BN, ng * 8), gblk, 0, stream>>>(
                H, w2t, b2, out + (size_t)g0 * Cap * D, D, F, g0, 1, 2048);
        }
    } else {
        // LEAN path: per-expert, both b-groups batched.  ~59 MB of ws.
        unsigned short* w1t = ws;                               // F*D
        unsigned short* w2t = w1t + (size_t)F * D;              // D*F
        unsigned short* xb  = w2t + (size_t)D * F;              // 2*Cap*D
        unsigned short* H   = xb + 2 * (size_t)Cap * D;         // 2*Cap*F

        for (int e = 0; e < E; ++e) {
            transpose_cvt<<<dim3(F / 64, D / 64, 1), blk, 0, stream>>>(
                w1 + (size_t)e * D * F, w1t, D, F);
            transpose_cvt<<<dim3(D / 64, F / 64, 1), blk, 0, stream>>>(
                w2 + (size_t)e * F * D, w2t, F, D);
            for (int b = 0; b < Bdim; ++b)
                cvt_f32_bf16<<<(unsigned)(((size_t)Cap * D / 4 + 255) / 256), blk, 0, stream>>>(
                    x + ((size_t)b * T + (size_t)e * Cap) * D,
                    xb + (size_t)b * Cap * D, (long long)Cap * D);
            gemm_bt<true, false><<<dim3(F / BN, 16), gblk, 0, stream>>>(
                xb, w1t, b1, H, F, D, e, 0, 2048);
            gemm_bt<false, true><<<dim3(D / BN, 16), gblk, 0, stream>>>(
                H, w2t, b2, out + (size_t)e * Cap * D, D, F, e, 0, T);
        }
    }
}